// Round 11
// baseline (299.853 us; speedup 1.0000x reference)
//
#include <hip/hip_runtime.h>

#define SEQ 2048
#define DM  1024
#define NH  16
#define HDIM 64

typedef __bf16   bf16x8 __attribute__((ext_vector_type(8)));
typedef float    f32x4  __attribute__((ext_vector_type(4)));
typedef _Float16 half8  __attribute__((ext_vector_type(8)));
typedef _Float16 half4v __attribute__((ext_vector_type(4)));

// async global->LDS 16B (linear LDS dst = wave-uniform base + lane*16)
__device__ __forceinline__ void gload16(const void* g, void* l) {
    __builtin_amdgcn_global_load_lds(
        (const __attribute__((address_space(1))) unsigned int*)g,
        (__attribute__((address_space(3))) unsigned int*)l, 16, 0, 0);
}

// ------------------------------------------------ sentinel: zero the output
__global__ void zero_out(float* __restrict__ out, int n) {
    int i = blockIdx.x * 256 + threadIdx.x;
    if (i < n) out[i] = 0.f;
}

// -------------- fused prep: [0,4096) cvt fp32->bf16 (6 weights + hs x2);
//                [4096,5120) Wsup = blockdiag(mixW)@Wv (+bsup);
//                [5120,7168) amp/phase -> cAT/sAT ([h][s] layout)
struct PrepArgs {
    const float* csrc[8]; __bf16* cdst[8];
    const float* mixw; const float* Wv; const float* bv; const float* mixb;
    __bf16* w6; float* bsup;
    const float* hs;
    const float* amp_w; const float* amp_b;
    const float* ph_w;  const float* ph_b;
    float* cAT; float* sAT;
};
__global__ __launch_bounds__(256) void prep_all(PrepArgs p) {
    const int tid = threadIdx.x, bid = blockIdx.x;
    if (bid < 4096) {
        const int z = bid >> 9;
        const int i = (bid & 511) * 256 + tid;
        const float4* s = reinterpret_cast<const float4*>(p.csrc[z]) + (size_t)i * 2;
        float4 x = s[0], y = s[1];
        bf16x8 o;
        o[0] = (__bf16)x.x; o[1] = (__bf16)x.y; o[2] = (__bf16)x.z; o[3] = (__bf16)x.w;
        o[4] = (__bf16)y.x; o[5] = (__bf16)y.y; o[6] = (__bf16)y.z; o[7] = (__bf16)y.w;
        reinterpret_cast<bf16x8*>(p.cdst[z])[i] = o;
    } else if (bid < 5120) {
        const int ho = bid - 4096, h = ho >> 6;
        __shared__ float mrow[64];
        if (tid < 64) mrow[tid] = p.mixw[(size_t)ho * 64 + tid];
        __syncthreads();
        const int c0 = tid * 4;
        float a0 = 0.f, a1 = 0.f, a2 = 0.f, a3 = 0.f;
        for (int dd = 0; dd < 64; ++dd) {
            const float4 wv4 = *reinterpret_cast<const float4*>(
                p.Wv + (size_t)(h * 64 + dd) * DM + c0);
            const float w = mrow[dd];
            a0 += w * wv4.x; a1 += w * wv4.y; a2 += w * wv4.z; a3 += w * wv4.w;
        }
        __bf16* dst = p.w6 + (size_t)ho * DM + c0;
        dst[0] = (__bf16)a0; dst[1] = (__bf16)a1;
        dst[2] = (__bf16)a2; dst[3] = (__bf16)a3;
        if (tid == 0) {
            float b = p.mixb[ho];
            for (int dd = 0; dd < 64; ++dd) b += mrow[dd] * p.bv[h * 64 + dd];
            p.bsup[ho] = b;
        }
    } else {
        const int s = bid - 5120;
        __shared__ float hrow[DM];
        for (int i = tid; i < DM; i += 256)
            hrow[i] = p.hs[(size_t)s * DM + i];
        __syncthreads();
        const int h = tid >> 4, sub = tid & 15;
        const float* aw = p.amp_w + (size_t)h * DM;
        const float* pw = p.ph_w  + (size_t)h * DM;
        float da = 0.f, dp = 0.f;
        for (int kx = sub; kx < DM; kx += 16) {
            const float hv = hrow[kx];
            da += hv * aw[kx];
            dp += hv * pw[kx];
        }
#pragma unroll
        for (int off = 8; off >= 1; off >>= 1) {
            da += __shfl_xor(da, off);
            dp += __shfl_xor(dp, off);
        }
        if (sub == 0) {
            da += p.amp_b[h]; dp += p.ph_b[h];
            float amp = 1.f / (1.f + expf(-da));
            float ph  = tanhf(dp) * 3.14159265358979323846f;
            p.cAT[(size_t)h * SEQ + s] = 0.3f * amp * cosf(ph);
            p.sAT[(size_t)h * SEQ + s] = 0.3f * amp * sinf(ph);
        }
    }
}

// ---------------------------------------------------------------- MFMA GEMM
// C[m][n] = sum_k A[m][k] * W[n][k] + bias[n]   (B^T layout: both K-contig)
// BK=32, global_load_lds(16B), source-side XOR swizzle (r4-proven).
// mode 2: f32 + resid add; mode 3: f16 row-major; mode 4: f16 TRANSPOSED
// ([col][SEQ] layout, s-contiguous half4 stores) for the mixer inputs.
// NOTE r9 lesson: folding the mixer into this kernel (static +16KB LDS)
// halved gemm occupancy and regressed — keep the epilogue lean.
struct GemmBatch {
    const __bf16* A;
    const __bf16* W[6];
    const float*  bias[6];
    void*         out[6];
    int           mode[6];
    const float*  resid;
};

__device__ __forceinline__ int swz4(int r) { return (r ^ (r >> 2)) & 3; }

__global__ __launch_bounds__(256) void gemm_bt(GemmBatch g) {
    const int z = blockIdx.z;
    const __bf16* __restrict__ A = g.A;
    const __bf16* __restrict__ W = g.W[z];
    const int ncol0 = blockIdx.x * 128;
    const int mrow0 = blockIdx.y * 128;
    const int tid = threadIdx.x, lane = tid & 63, wv = tid >> 6;
    const int wm = wv >> 1, wn = wv & 1;
    const int fr = lane & 15, fj = lane >> 4;

    __shared__ __bf16 As[128 * 32];
    __shared__ __bf16 Bs[128 * 32];

    f32x4 acc[4][4];
#pragma unroll
    for (int i = 0; i < 4; ++i)
#pragma unroll
        for (int j = 0; j < 4; ++j)
#pragma unroll
            for (int e = 0; e < 4; ++e) acc[i][j][e] = 0.f;

    const int row0 = wv * 16 + (lane >> 2);
    const int row1 = row0 + 64;
    const int jl   = lane & 3;
    const int dstA0 = row0 * 32 + jl * 8;
    const int dstA1 = row1 * 32 + jl * 8;
    const __bf16* ApS0 = A + (size_t)(mrow0 + row0) * DM + (jl ^ swz4(row0)) * 8;
    const __bf16* ApS1 = A + (size_t)(mrow0 + row1) * DM + (jl ^ swz4(row1)) * 8;
    const __bf16* WpS0 = W + (size_t)(ncol0 + row0) * DM + (jl ^ swz4(row0)) * 8;
    const __bf16* WpS1 = W + (size_t)(ncol0 + row1) * DM + (jl ^ swz4(row1)) * 8;

    for (int kt = 0; kt < DM; kt += 32) {
        __syncthreads();
        gload16(ApS0 + kt, As + dstA0);
        gload16(ApS1 + kt, As + dstA1);
        gload16(WpS0 + kt, Bs + dstA0);
        gload16(WpS1 + kt, Bs + dstA1);
        __syncthreads();

        bf16x8 af[4], bfv[4];
#pragma unroll
        for (int mf = 0; mf < 4; ++mf) {
            int r = wm * 64 + mf * 16 + fr;
            af[mf] = *(const bf16x8*)(As + r * 32 + ((fj ^ swz4(r)) << 3));
        }
#pragma unroll
        for (int nf = 0; nf < 4; ++nf) {
            int r = wn * 64 + nf * 16 + fr;
            bfv[nf] = *(const bf16x8*)(Bs + r * 32 + ((fj ^ swz4(r)) << 3));
        }
#pragma unroll
        for (int mf = 0; mf < 4; ++mf)
#pragma unroll
            for (int nf = 0; nf < 4; ++nf)
                acc[mf][nf] = __builtin_amdgcn_mfma_f32_16x16x32_bf16(
                    af[mf], bfv[nf], acc[mf][nf], 0, 0, 0);
    }

    const int mode = g.mode[z];
    const float* __restrict__ bias = g.bias[z];
#pragma unroll
    for (int mf = 0; mf < 4; ++mf) {
#pragma unroll
        for (int nf = 0; nf < 4; ++nf) {
            const int col = ncol0 + wn * 64 + nf * 16 + fr;
            const int rw0 = mrow0 + wm * 64 + mf * 16 + fj * 4;
            const float bc = bias[col];
            float v4[4];
#pragma unroll
            for (int jj = 0; jj < 4; ++jj) v4[jj] = acc[mf][nf][jj] + bc;
            if (mode == 4) {
                half4v t;
#pragma unroll
                for (int jj = 0; jj < 4; ++jj) t[jj] = (_Float16)v4[jj];
                *(half4v*)((_Float16*)g.out[z] + (size_t)col * SEQ + rw0) = t;
            } else if (mode == 3) {
#pragma unroll
                for (int jj = 0; jj < 4; ++jj)
                    ((_Float16*)g.out[z])[(size_t)(rw0 + jj) * DM + col] = (_Float16)v4[jj];
            } else {
#pragma unroll
                for (int jj = 0; jj < 4; ++jj) {
                    const size_t idx = (size_t)(rw0 + jj) * DM + col;
                    float vv = v4[jj];
                    if (mode == 2) vv += g.resid[idx];
                    ((float*)g.out[z])[idx] = vv;
                }
            }
        }
    }
}

// ---------------------------------------------------- flash MFMA attention
// r4-proven structure: 64 q-rows x 1 head, 4 waves x 16 q-rows, KV tiles 64,
// single-buffered K/E/M with register prefetch, defer-max online softmax
// (m0=0, THR=8), band sparsity (|delta|>160 skip).
// XCD-aware 1-D grid (r9-proven: FETCH 50.5->10.3 MB): h=(bid&7)+8*(bid>>8),
// q0=((bid>>3)&31)*64 — a head's 32 q-blocks land on one XCD (L2-resident).
// MIXER FUSED (r11): the mixedT tile is computed on the fly in the register
// prefetch phase from vT/supT/cA/sA (all L2-resident per-XCD under the
// swizzle); math identical to the removed mixT2 kernel (same f16 roundings).
__global__ __launch_bounds__(256) void attn_mfma(
    const _Float16* __restrict__ q, const _Float16* __restrict__ k,
    const _Float16* __restrict__ eq, const _Float16* __restrict__ ek,
    const _Float16* __restrict__ vT, const _Float16* __restrict__ supT,
    const float* __restrict__ cAT, const float* __restrict__ sAT,
    __bf16* __restrict__ ctx)
{
    const int bid = blockIdx.x;
    const int h  = (bid & 7) + ((bid >> 8) << 3);
    const int q0 = ((bid >> 3) & 31) * 64;
    const int tid = threadIdx.x, lane = tid & 63, wv = tid >> 6;
    const int lo = lane & 15, hi = lane >> 4;
    const int hoff = h * HDIM;

    __shared__ _Float16 Kt[64 * 64];
    __shared__ _Float16 Et[64 * 64];
    __shared__ _Float16 Mt[64 * 64];
    __shared__ _Float16 Pt[4][64 * 18];    // per-wave [64key][16row+2pad]

    half8 qa[2], ea[2];
#pragma unroll
    for (int kk = 0; kk < 2; ++kk) {
        const int row = q0 + wv * 16 + lo;
        qa[kk] = *(const half8*)(q  + (size_t)row * DM + hoff + kk * 32 + hi * 8);
        ea[kk] = *(const half8*)(eq + (size_t)row * DM + hoff + kk * 32 + hi * 8);
    }

    f32x4 oacc[4];
    float mr[4], lr[4];
#pragma unroll
    for (int j = 0; j < 4; ++j) { mr[j] = 0.f; lr[j] = 0.f; }
#pragma unroll
    for (int n = 0; n < 4; ++n)
#pragma unroll
        for (int e = 0; e < 4; ++e) oacc[n][e] = 0.f;

    const int srow = tid >> 3, schk = tid & 7;
    const int sdst0 = srow * 64 + ((schk ^ (srow & 7)) << 3);
    const int sdst1 = (srow + 32) * 64 + ((schk ^ (srow & 7)) << 3);

    // mix-on-the-fly: m[o][s] = v + cA*sup + sA*sup[(o+63)&63]
    #define LOADMIX(nt_, m0_, m1_) do {                                          \
        const size_t sb_ = (size_t)(nt_) + schk * 8;                             \
        const half8 v0_ = *(const half8*)(vT   + (size_t)(hoff + srow) * SEQ + sb_);            \
        const half8 v1_ = *(const half8*)(vT   + (size_t)(hoff + srow + 32) * SEQ + sb_);       \
        const half8 s0_ = *(const half8*)(supT + (size_t)(hoff + srow) * SEQ + sb_);            \
        const half8 s1_ = *(const half8*)(supT + (size_t)(hoff + srow + 32) * SEQ + sb_);       \
        const half8 r0_ = *(const half8*)(supT + (size_t)(hoff + ((srow + 63) & 63)) * SEQ + sb_); \
        const half8 r1_ = *(const half8*)(supT + (size_t)(hoff + srow + 31) * SEQ + sb_);       \
        const float4 c0_ = *(const float4*)(cAT + (size_t)h * SEQ + sb_);        \
        const float4 c1_ = *(const float4*)(cAT + (size_t)h * SEQ + sb_ + 4);    \
        const float4 a0_ = *(const float4*)(sAT + (size_t)h * SEQ + sb_);        \
        const float4 a1_ = *(const float4*)(sAT + (size_t)h * SEQ + sb_ + 4);    \
        const float caw_[8] = {c0_.x, c0_.y, c0_.z, c0_.w, c1_.x, c1_.y, c1_.z, c1_.w}; \
        const float saw_[8] = {a0_.x, a0_.y, a0_.z, a0_.w, a1_.x, a1_.y, a1_.z, a1_.w}; \
        _Pragma("unroll")                                                        \
        for (int e_ = 0; e_ < 8; ++e_) {                                         \
            m0_[e_] = (_Float16)((float)v0_[e_] + caw_[e_] * (float)s0_[e_]      \
                                 + saw_[e_] * (float)r0_[e_]);                   \
            m1_[e_] = (_Float16)((float)v1_[e_] + caw_[e_] * (float)s1_[e_]      \
                                 + saw_[e_] * (float)r1_[e_]);                   \
        }                                                                        \
    } while (0)

    #define IN_BAND(kt_) ({ int _a = (kt_) - (q0 + 63); int _b = q0 - ((kt_) + 63); \
                            int _d = _a > 0 ? _a : (_b > 0 ? _b : 0); _d <= 160; })

    bool diagCur = IN_BAND(0);
    half8 rk0 = *(const half8*)(k  + (size_t)(srow) * DM + hoff + schk * 8);
    half8 rk1 = *(const half8*)(k  + (size_t)(srow + 32) * DM + hoff + schk * 8);
    half8 rm0, rm1;
    LOADMIX(0, rm0, rm1);
    half8 re0, re1;
    if (diagCur) {
        re0 = *(const half8*)(ek + (size_t)(srow) * DM + hoff + schk * 8);
        re1 = *(const half8*)(ek + (size_t)(srow + 32) * DM + hoff + schk * 8);
    }

    for (int kt = 0; kt < SEQ; kt += 64) {
        __syncthreads();
        *(half8*)&Kt[sdst0] = rk0; *(half8*)&Kt[sdst1] = rk1;
        *(half8*)&Mt[sdst0] = rm0; *(half8*)&Mt[sdst1] = rm1;
        if (diagCur) { *(half8*)&Et[sdst0] = re0; *(half8*)&Et[sdst1] = re1; }
        __syncthreads();
        const bool diagNext = (kt + 64 < SEQ) && IN_BAND(kt + 64);
        if (kt + 64 < SEQ) {
            const int nt = kt + 64;
            rk0 = *(const half8*)(k  + (size_t)(nt + srow) * DM + hoff + schk * 8);
            rk1 = *(const half8*)(k  + (size_t)(nt + srow + 32) * DM + hoff + schk * 8);
            LOADMIX(nt, rm0, rm1);
            if (diagNext) {
                re0 = *(const half8*)(ek + (size_t)(nt + srow) * DM + hoff + schk * 8);
                re1 = *(const half8*)(ek + (size_t)(nt + srow + 32) * DM + hoff + schk * 8);
            }
        }

        // ---- QK^T (always) and EQ*EK^T (band tiles only)
        f32x4 sa[4], se[4];
#pragma unroll
        for (int n = 0; n < 4; ++n)
#pragma unroll
            for (int e = 0; e < 4; ++e) { sa[n][e] = 0.f; se[n][e] = 0.f; }
#pragma unroll
        for (int kk = 0; kk < 2; ++kk)
#pragma unroll
            for (int nf = 0; nf < 4; ++nf) {
                const int rrow = lo + 16 * nf;
                const int coff = rrow * 64 + (((hi + 4 * kk) ^ (rrow & 7)) << 3);
                half8 kb = *(const half8*)&Kt[coff];
                sa[nf] = __builtin_amdgcn_mfma_f32_16x16x32_f16(qa[kk], kb, sa[nf], 0, 0, 0);
            }
        if (diagCur) {
#pragma unroll
            for (int kk = 0; kk < 2; ++kk)
#pragma unroll
                for (int nf = 0; nf < 4; ++nf) {
                    const int rrow = lo + 16 * nf;
                    const int coff = rrow * 64 + (((hi + 4 * kk) ^ (rrow & 7)) << 3);
                    half8 eb = *(const half8*)&Et[coff];
                    se[nf] = __builtin_amdgcn_mfma_f32_16x16x32_f16(ea[kk], eb, se[nf], 0, 0, 0);
                }
        }

        // ---- logits + defer-max check
        float lg[4][4];
        bool exc = false;
        const int qrow = q0 + wv * 16 + hi * 4;
        if (diagCur) {
#pragma unroll
            for (int nf = 0; nf < 4; ++nf) {
                const int key = kt + nf * 16 + lo;
#pragma unroll
                for (int j = 0; j < 4; ++j) {
                    int dd = qrow + j - key; dd = dd < 0 ? -dd : dd;
                    const float dec = exp2f(-0.14426950408889634f * (float)dd);
                    const float v = 0.125f * sa[nf][j] + 0.0625f * se[nf][j] * dec;
                    lg[nf][j] = v;
                    exc |= (v > mr[j] + 8.f);
                }
            }
        } else {
#pragma unroll
            for (int nf = 0; nf < 4; ++nf)
#pragma unroll
                for (int j = 0; j < 4; ++j) {
                    const float v = 0.125f * sa[nf][j];
                    lg[nf][j] = v;
                    exc |= (v > mr[j] + 8.f);
                }
        }
        if (__any((int)exc)) {                       // rare rescale path
#pragma unroll
            for (int j = 0; j < 4; ++j) {
                float tm = fmaxf(fmaxf(lg[0][j], lg[1][j]), fmaxf(lg[2][j], lg[3][j]));
#pragma unroll
                for (int off = 8; off >= 1; off >>= 1) tm = fmaxf(tm, __shfl_xor(tm, off));
                const float mnew = fmaxf(mr[j], tm);
                const float corr = __expf(mr[j] - mnew);
                lr[j] *= corr; mr[j] = mnew;
#pragma unroll
                for (int nfd = 0; nfd < 4; ++nfd) oacc[nfd][j] *= corr;
            }
        }
        // ---- P = exp(lg - m), lane-local l accumulation, P -> LDS (f16)
        _Float16* Pw = Pt[wv];
#pragma unroll
        for (int nf = 0; nf < 4; ++nf) {
            half4v pv;
#pragma unroll
            for (int j = 0; j < 4; ++j) {
                const float p = __expf(lg[nf][j] - mr[j]);
                lr[j] += p;
                pv[j] = (_Float16)p;
            }
            *(half4v*)&Pw[(lo + 16 * nf) * 18 + hi * 4] = pv;
        }
        __asm__ volatile("s_waitcnt lgkmcnt(0)" ::: "memory");

        // ---- PV: oacc += P * mixed
#pragma unroll
        for (int kk = 0; kk < 2; ++kk) {
            half8 mb[4];
#pragma unroll
            for (int nfd = 0; nfd < 4; ++nfd) {
                const int rrow = lo + 16 * nfd;
                mb[nfd] = *(const half8*)&Mt[rrow * 64 + (((hi + 4 * kk) ^ (rrow & 7)) << 3)];
            }
            half8 pa;
#pragma unroll
            for (int e = 0; e < 8; ++e)
                pa[e] = Pw[(kk * 32 + hi * 8 + e) * 18 + lo];
#pragma unroll
            for (int nfd = 0; nfd < 4; ++nfd)
                oacc[nfd] = __builtin_amdgcn_mfma_f32_16x16x32_f16(pa, mb[nfd], oacc[nfd], 0, 0, 0);
        }
        diagCur = diagNext;
    }
    #undef IN_BAND
    #undef LOADMIX

    // ---- epilogue: reduce l over the 16-lane row group, normalize, store
#pragma unroll
    for (int j = 0; j < 4; ++j) {
#pragma unroll
        for (int off = 8; off >= 1; off >>= 1) lr[j] += __shfl_xor(lr[j], off);
    }
    const int qrow = q0 + wv * 16 + hi * 4;
#pragma unroll
    for (int nfd = 0; nfd < 4; ++nfd) {
        const int d = hoff + lo + 16 * nfd;
#pragma unroll
        for (int j = 0; j < 4; ++j)
            ctx[(size_t)(qrow + j) * DM + d] = (__bf16)(oacc[nfd][j] / lr[j]);
    }
}

// --------------------------------------------- layer norm, FP32 OUTPUT
__global__ __launch_bounds__(256) void lnorm_f32(
    const float* __restrict__ res, const float* __restrict__ g,
    const float* __restrict__ b, float* __restrict__ out)
{
    const int row = blockIdx.x, tid = threadIdx.x;
    const int wave = tid >> 6, lane = tid & 63;
    __shared__ float red[8];
    const float4 x = reinterpret_cast<const float4*>(res + (size_t)row * DM)[tid];
    float s  = x.x + x.y + x.z + x.w;
    float s2 = x.x * x.x + x.y * x.y + x.z * x.z + x.w * x.w;
#pragma unroll
    for (int off = 32; off >= 1; off >>= 1) {
        s  += __shfl_xor(s, off);
        s2 += __shfl_xor(s2, off);
    }
    if (lane == 0) { red[wave] = s; red[4 + wave] = s2; }
    __syncthreads();
    s  = red[0] + red[1] + red[2] + red[3];
    s2 = red[4] + red[5] + red[6] + red[7];
    const float mu  = s * (1.f / DM);
    const float var = s2 * (1.f / DM) - mu * mu;
    const float inv = rsqrtf(var + 1e-5f);
    const int col = tid * 4;
    float4 o;
    o.x = (x.x - mu) * inv * g[col + 0] + b[col + 0];
    o.y = (x.y - mu) * inv * g[col + 1] + b[col + 1];
    o.z = (x.z - mu) * inv * g[col + 2] + b[col + 2];
    o.w = (x.w - mu) * inv * g[col + 3] + b[col + 3];
    reinterpret_cast<float4*>(out + (size_t)row * DM)[tid] = o;
}

// ---------------------------------------------------------------- launch
// OUTPUT IS FP32. 5 dispatches: prep_all, g1, attn (mixer fused), g3, lnorm.
// ws layout (~34.3 MB):
//   [0,4M)    hsb bf16        -> overlaid by ctx bf16 (hsb dead after g1)
//   [4,16M)   w0..w5 bf16 (Wq,Wk,Wv,Weq,Wek,Wo), 2MB each
//   [16,18M)  w6 = Wsup bf16
//   [18,22M)  qf f16   [22,26M) kf f16   } res f32 overlays [18,26M) post-attn
//   [26,30M)  eqf f16  [30,34M) ekf f16
//   [34M..)   cAT (128K), sAT (128K), bsup (4K)   ([h][s] layout)
// d_out staging: vT f16 [0,4M), supT f16 [4,8M) (TRANSPOSED [col][s]) —
// live through attn (mixer fused there); lnorm rewrites full 8MB fp32 last.
extern "C" void kernel_launch(void* const* d_in, const int* in_sizes, int n_in,
                              void* d_out, int out_size, void* d_ws, size_t ws_size,
                              hipStream_t stream) {
    const float* hs   = (const float*)d_in[0];
    const float* Wq   = (const float*)d_in[1];
    const float* bq   = (const float*)d_in[2];
    const float* Wk   = (const float*)d_in[3];
    const float* bk   = (const float*)d_in[4];
    const float* Wv   = (const float*)d_in[5];
    const float* bv   = (const float*)d_in[6];
    const float* Wo   = (const float*)d_in[7];
    const float* bo   = (const float*)d_in[8];
    const float* Weq  = (const float*)d_in[9];
    const float* beq  = (const float*)d_in[10];
    const float* Wek  = (const float*)d_in[11];
    const float* bek  = (const float*)d_in[12];
    const float* ampw = (const float*)d_in[13];
    const float* ampb = (const float*)d_in[14];
    const float* phw  = (const float*)d_in[15];
    const float* phb  = (const float*)d_in[16];
    const float* mixw = (const float*)d_in[17];
    const float* mixb = (const float*)d_in[18];
    const float* lng  = (const float*)d_in[19];
    const float* lnb  = (const float*)d_in[20];
    float* out = (float*)d_out;

    static const int expect[21] = {
        2097152, 1048576, 1024, 1048576, 1024, 1048576, 1024, 1048576, 1024,
        1048576, 1024, 1048576, 1024, 16384, 16, 16384, 16, 65536, 1024,
        1024, 1024};
    bool ok = (n_in == 21) && (out_size == 2097152);
    if (ok) for (int i = 0; i < 21; ++i) ok = ok && (in_sizes[i] == expect[i]);
    if (!ok) {
        zero_out<<<(out_size + 255) / 256, 256, 0, stream>>>(out, out_size);
        return;
    }

    char* ws = (char*)d_ws;
    __bf16*   hsb = (__bf16*)ws;
    __bf16*   w0  = (__bf16*)(ws + (4  << 20));
    __bf16*   w1  = (__bf16*)(ws + (6  << 20));
    __bf16*   w2  = (__bf16*)(ws + (8  << 20));
    __bf16*   w3  = (__bf16*)(ws + (10 << 20));
    __bf16*   w4  = (__bf16*)(ws + (12 << 20));
    __bf16*   w5  = (__bf16*)(ws + (14 << 20));
    __bf16*   w6  = (__bf16*)(ws + (16 << 20));
    _Float16* qf  = (_Float16*)(ws + (18 << 20));
    _Float16* kf  = (_Float16*)(ws + (22 << 20));
    _Float16* eqf = (_Float16*)(ws + (26 << 20));
    _Float16* ekf = (_Float16*)(ws + (30 << 20));
    float*    cAT = (float*)(ws + (34 << 20));
    float*    sAT = cAT + SEQ * NH;
    float*    bsup = sAT + SEQ * NH;
    __bf16*   ctx = hsb;                       // overlay: hsb dead after g1
    float*    res = (float*)(ws + (18 << 20)); // overlay: q/k dead after attn
    _Float16* vT   = (_Float16*)d_out;
    _Float16* supT = (_Float16*)((char*)d_out + (4 << 20));

    PrepArgs p;
    p.csrc[0] = Wq;  p.cdst[0] = w0;
    p.csrc[1] = Wk;  p.cdst[1] = w1;
    p.csrc[2] = Wv;  p.cdst[2] = w2;
    p.csrc[3] = Weq; p.cdst[3] = w3;
    p.csrc[4] = Wek; p.cdst[4] = w4;
    p.csrc[5] = Wo;  p.cdst[5] = w5;
    p.csrc[6] = hs;                p.cdst[6] = hsb;
    p.csrc[7] = hs + SEQ * DM / 2; p.cdst[7] = hsb + SEQ * DM / 2;
    p.mixw = mixw; p.Wv = Wv; p.bv = bv; p.mixb = mixb;
    p.w6 = w6; p.bsup = bsup;
    p.hs = hs;
    p.amp_w = ampw; p.amp_b = ampb; p.ph_w = phw; p.ph_b = phb;
    p.cAT = cAT; p.sAT = sAT;
    prep_all<<<7168, 256, 0, stream>>>(p);

    GemmBatch g1 = {};
    g1.A = hsb;
    g1.W[0] = w0; g1.bias[0] = bq;   g1.out[0] = qf;   g1.mode[0] = 3;
    g1.W[1] = w1; g1.bias[1] = bk;   g1.out[1] = kf;   g1.mode[1] = 3;
    g1.W[2] = w2; g1.bias[2] = bv;   g1.out[2] = vT;   g1.mode[2] = 4;
    g1.W[3] = w3; g1.bias[3] = beq;  g1.out[3] = eqf;  g1.mode[3] = 3;
    g1.W[4] = w4; g1.bias[4] = bek;  g1.out[4] = ekf;  g1.mode[4] = 3;
    g1.W[5] = w6; g1.bias[5] = bsup; g1.out[5] = supT; g1.mode[5] = 4;
    g1.resid = nullptr;
    gemm_bt<<<dim3(DM / 128, SEQ / 128, 6), 256, 0, stream>>>(g1);

    attn_mfma<<<512, 256, 0, stream>>>(qf, kf, eqf, ekf, vT, supT, cAT, sAT, ctx);

    GemmBatch g3 = {};
    g3.A = ctx;
    g3.W[0] = w5; g3.bias[0] = bo; g3.out[0] = res; g3.mode[0] = 2;
    g3.resid = hs;
    gemm_bt<<<dim3(DM / 128, SEQ / 128, 1), 256, 0, stream>>>(g3);

    lnorm_f32<<<SEQ, 256, 0, stream>>>(res, lng, lnb, out);
}

// Round 12
// 290.799 us; speedup vs baseline: 1.0311x; 1.0311x over previous
//
#include <hip/hip_runtime.h>

#define SEQ 2048
#define DM  1024
#define NH  16
#define HDIM 64

typedef __bf16   bf16x8 __attribute__((ext_vector_type(8)));
typedef float    f32x4  __attribute__((ext_vector_type(4)));
typedef _Float16 half8  __attribute__((ext_vector_type(8)));
typedef _Float16 half4v __attribute__((ext_vector_type(4)));

// async global->LDS 16B (linear LDS dst = wave-uniform base + lane*16)
__device__ __forceinline__ void gload16(const void* g, void* l) {
    __builtin_amdgcn_global_load_lds(
        (const __attribute__((address_space(1))) unsigned int*)g,
        (__attribute__((address_space(3))) unsigned int*)l, 16, 0, 0);
}

// ------------------------------------------------ sentinel: zero the output
__global__ void zero_out(float* __restrict__ out, int n) {
    int i = blockIdx.x * 256 + threadIdx.x;
    if (i < n) out[i] = 0.f;
}

// -------------- fused prep: [0,4096) cvt fp32->bf16 (6 weights + hs x2);
//                [4096,5120) Wsup = blockdiag(mixW)@Wv (+bsup);
//                [5120,7168) amp/phase -> cAT/sAT ([h][s] layout)
struct PrepArgs {
    const float* csrc[8]; __bf16* cdst[8];
    const float* mixw; const float* Wv; const float* bv; const float* mixb;
    __bf16* w6; float* bsup;
    const float* hs;
    const float* amp_w; const float* amp_b;
    const float* ph_w;  const float* ph_b;
    float* cAT; float* sAT;
};
__global__ __launch_bounds__(256) void prep_all(PrepArgs p) {
    const int tid = threadIdx.x, bid = blockIdx.x;
    if (bid < 4096) {
        const int z = bid >> 9;
        const int i = (bid & 511) * 256 + tid;
        const float4* s = reinterpret_cast<const float4*>(p.csrc[z]) + (size_t)i * 2;
        float4 x = s[0], y = s[1];
        bf16x8 o;
        o[0] = (__bf16)x.x; o[1] = (__bf16)x.y; o[2] = (__bf16)x.z; o[3] = (__bf16)x.w;
        o[4] = (__bf16)y.x; o[5] = (__bf16)y.y; o[6] = (__bf16)y.z; o[7] = (__bf16)y.w;
        reinterpret_cast<bf16x8*>(p.cdst[z])[i] = o;
    } else if (bid < 5120) {
        const int ho = bid - 4096, h = ho >> 6;
        __shared__ float mrow[64];
        if (tid < 64) mrow[tid] = p.mixw[(size_t)ho * 64 + tid];
        __syncthreads();
        const int c0 = tid * 4;
        float a0 = 0.f, a1 = 0.f, a2 = 0.f, a3 = 0.f;
        for (int dd = 0; dd < 64; ++dd) {
            const float4 wv4 = *reinterpret_cast<const float4*>(
                p.Wv + (size_t)(h * 64 + dd) * DM + c0);
            const float w = mrow[dd];
            a0 += w * wv4.x; a1 += w * wv4.y; a2 += w * wv4.z; a3 += w * wv4.w;
        }
        __bf16* dst = p.w6 + (size_t)ho * DM + c0;
        dst[0] = (__bf16)a0; dst[1] = (__bf16)a1;
        dst[2] = (__bf16)a2; dst[3] = (__bf16)a3;
        if (tid == 0) {
            float b = p.mixb[ho];
            for (int dd = 0; dd < 64; ++dd) b += mrow[dd] * p.bv[h * 64 + dd];
            p.bsup[ho] = b;
        }
    } else {
        const int s = bid - 5120;
        __shared__ float hrow[DM];
        for (int i = tid; i < DM; i += 256)
            hrow[i] = p.hs[(size_t)s * DM + i];
        __syncthreads();
        const int h = tid >> 4, sub = tid & 15;
        const float* aw = p.amp_w + (size_t)h * DM;
        const float* pw = p.ph_w  + (size_t)h * DM;
        float da = 0.f, dp = 0.f;
        for (int kx = sub; kx < DM; kx += 16) {
            const float hv = hrow[kx];
            da += hv * aw[kx];
            dp += hv * pw[kx];
        }
#pragma unroll
        for (int off = 8; off >= 1; off >>= 1) {
            da += __shfl_xor(da, off);
            dp += __shfl_xor(dp, off);
        }
        if (sub == 0) {
            da += p.amp_b[h]; dp += p.ph_b[h];
            float amp = 1.f / (1.f + expf(-da));
            float ph  = tanhf(dp) * 3.14159265358979323846f;
            p.cAT[(size_t)h * SEQ + s] = 0.3f * amp * cosf(ph);
            p.sAT[(size_t)h * SEQ + s] = 0.3f * amp * sinf(ph);
        }
    }
}

// ---------------------------------------------------------------- MFMA GEMM
// C[m][n] = sum_k A[m][k] * W[n][k] + bias[n]   (B^T layout: both K-contig)
// BK=32, global_load_lds(16B), source-side XOR swizzle (r4-proven).
// mode 2: f32 + resid add; mode 3: f16 row-major; mode 4: f16 TRANSPOSED
// ([col][SEQ] layout, s-contiguous half4 stores) for the mixer inputs.
// NOTE r9/r11 lesson: folding the mixer into gemm or attn regressed both
// times (occupancy / critical-path cost > ~10us launch saving) — keep lean.
struct GemmBatch {
    const __bf16* A;
    const __bf16* W[6];
    const float*  bias[6];
    void*         out[6];
    int           mode[6];
    const float*  resid;
};

__device__ __forceinline__ int swz4(int r) { return (r ^ (r >> 2)) & 3; }

__global__ __launch_bounds__(256) void gemm_bt(GemmBatch g) {
    const int z = blockIdx.z;
    const __bf16* __restrict__ A = g.A;
    const __bf16* __restrict__ W = g.W[z];
    const int ncol0 = blockIdx.x * 128;
    const int mrow0 = blockIdx.y * 128;
    const int tid = threadIdx.x, lane = tid & 63, wv = tid >> 6;
    const int wm = wv >> 1, wn = wv & 1;
    const int fr = lane & 15, fj = lane >> 4;

    __shared__ __bf16 As[128 * 32];
    __shared__ __bf16 Bs[128 * 32];

    f32x4 acc[4][4];
#pragma unroll
    for (int i = 0; i < 4; ++i)
#pragma unroll
        for (int j = 0; j < 4; ++j)
#pragma unroll
            for (int e = 0; e < 4; ++e) acc[i][j][e] = 0.f;

    const int row0 = wv * 16 + (lane >> 2);
    const int row1 = row0 + 64;
    const int jl   = lane & 3;
    const int dstA0 = row0 * 32 + jl * 8;
    const int dstA1 = row1 * 32 + jl * 8;
    const __bf16* ApS0 = A + (size_t)(mrow0 + row0) * DM + (jl ^ swz4(row0)) * 8;
    const __bf16* ApS1 = A + (size_t)(mrow0 + row1) * DM + (jl ^ swz4(row1)) * 8;
    const __bf16* WpS0 = W + (size_t)(ncol0 + row0) * DM + (jl ^ swz4(row0)) * 8;
    const __bf16* WpS1 = W + (size_t)(ncol0 + row1) * DM + (jl ^ swz4(row1)) * 8;

    for (int kt = 0; kt < DM; kt += 32) {
        __syncthreads();
        gload16(ApS0 + kt, As + dstA0);
        gload16(ApS1 + kt, As + dstA1);
        gload16(WpS0 + kt, Bs + dstA0);
        gload16(WpS1 + kt, Bs + dstA1);
        __syncthreads();

        bf16x8 af[4], bfv[4];
#pragma unroll
        for (int mf = 0; mf < 4; ++mf) {
            int r = wm * 64 + mf * 16 + fr;
            af[mf] = *(const bf16x8*)(As + r * 32 + ((fj ^ swz4(r)) << 3));
        }
#pragma unroll
        for (int nf = 0; nf < 4; ++nf) {
            int r = wn * 64 + nf * 16 + fr;
            bfv[nf] = *(const bf16x8*)(Bs + r * 32 + ((fj ^ swz4(r)) << 3));
        }
#pragma unroll
        for (int mf = 0; mf < 4; ++mf)
#pragma unroll
            for (int nf = 0; nf < 4; ++nf)
                acc[mf][nf] = __builtin_amdgcn_mfma_f32_16x16x32_bf16(
                    af[mf], bfv[nf], acc[mf][nf], 0, 0, 0);
    }

    const int mode = g.mode[z];
    const float* __restrict__ bias = g.bias[z];
#pragma unroll
    for (int mf = 0; mf < 4; ++mf) {
#pragma unroll
        for (int nf = 0; nf < 4; ++nf) {
            const int col = ncol0 + wn * 64 + nf * 16 + fr;
            const int rw0 = mrow0 + wm * 64 + mf * 16 + fj * 4;
            const float bc = bias[col];
            float v4[4];
#pragma unroll
            for (int jj = 0; jj < 4; ++jj) v4[jj] = acc[mf][nf][jj] + bc;
            if (mode == 4) {
                half4v t;
#pragma unroll
                for (int jj = 0; jj < 4; ++jj) t[jj] = (_Float16)v4[jj];
                *(half4v*)((_Float16*)g.out[z] + (size_t)col * SEQ + rw0) = t;
            } else if (mode == 3) {
#pragma unroll
                for (int jj = 0; jj < 4; ++jj)
                    ((_Float16*)g.out[z])[(size_t)(rw0 + jj) * DM + col] = (_Float16)v4[jj];
            } else {
#pragma unroll
                for (int jj = 0; jj < 4; ++jj) {
                    const size_t idx = (size_t)(rw0 + jj) * DM + col;
                    float vv = v4[jj];
                    if (mode == 2) vv += g.resid[idx];
                    ((float*)g.out[z])[idx] = vv;
                }
            }
        }
    }
}

// ------------- mixedT[ho][s] = vT + cA*supT + sA*supT[roll]  (all coalesced)
__global__ __launch_bounds__(256) void mixT2(
    const _Float16* __restrict__ vT, const _Float16* __restrict__ supT,
    const float* __restrict__ cAT, const float* __restrict__ sAT,
    _Float16* __restrict__ mixedT)
{
    const int ho = blockIdx.x, h = ho >> 6, o = ho & 63;
    const int op = h * 64 + ((o + 63) & 63);
    const int s0 = threadIdx.x * 8;
    half8 v  = *(const half8*)(vT   + (size_t)ho * SEQ + s0);
    half8 su = *(const half8*)(supT + (size_t)ho * SEQ + s0);
    half8 s2 = *(const half8*)(supT + (size_t)op * SEQ + s0);
    const float4 c0 = *(const float4*)(cAT + (size_t)h * SEQ + s0);
    const float4 c1 = *(const float4*)(cAT + (size_t)h * SEQ + s0 + 4);
    const float4 a0 = *(const float4*)(sAT + (size_t)h * SEQ + s0);
    const float4 a1 = *(const float4*)(sAT + (size_t)h * SEQ + s0 + 4);
    const float ca[8] = {c0.x, c0.y, c0.z, c0.w, c1.x, c1.y, c1.z, c1.w};
    const float sa[8] = {a0.x, a0.y, a0.z, a0.w, a1.x, a1.y, a1.z, a1.w};
    half8 m;
#pragma unroll
    for (int e = 0; e < 8; ++e)
        m[e] = (_Float16)((float)v[e] + ca[e] * (float)su[e] + sa[e] * (float)s2[e]);
    *(half8*)(mixedT + (size_t)ho * SEQ + s0) = m;
}

// ---------------------------------------------------- flash MFMA attention
// r4-proven structure: 64 q-rows x 1 head, 4 waves x 16 q-rows, KV tiles 64,
// single-buffered K/E/M with register prefetch, defer-max online softmax
// (m0=0, THR=8), band sparsity (|delta|>160 skip).
// XCD-aware 1-D grid (r9-proven: FETCH 50.5->10.3 MB, -9 us):
// h = (bid&7)+8*(bid>>8), q0 = ((bid>>3)&31)*64 — all 32 q-blocks of a
// head land on one XCD so its K/E/M stay resident in that L2.
__global__ __launch_bounds__(256) void attn_mfma(
    const _Float16* __restrict__ q, const _Float16* __restrict__ k,
    const _Float16* __restrict__ eq, const _Float16* __restrict__ ek,
    const _Float16* __restrict__ mixedT, __bf16* __restrict__ ctx)
{
    const int bid = blockIdx.x;
    const int h  = (bid & 7) + ((bid >> 8) << 3);
    const int q0 = ((bid >> 3) & 31) * 64;
    const int tid = threadIdx.x, lane = tid & 63, wv = tid >> 6;
    const int lo = lane & 15, hi = lane >> 4;
    const int hoff = h * HDIM;

    __shared__ _Float16 Kt[64 * 64];
    __shared__ _Float16 Et[64 * 64];
    __shared__ _Float16 Mt[64 * 64];
    __shared__ _Float16 Pt[4][64 * 18];    // per-wave [64key][16row+2pad]

    half8 qa[2], ea[2];
#pragma unroll
    for (int kk = 0; kk < 2; ++kk) {
        const int row = q0 + wv * 16 + lo;
        qa[kk] = *(const half8*)(q  + (size_t)row * DM + hoff + kk * 32 + hi * 8);
        ea[kk] = *(const half8*)(eq + (size_t)row * DM + hoff + kk * 32 + hi * 8);
    }

    f32x4 oacc[4];
    float mr[4], lr[4];
#pragma unroll
    for (int j = 0; j < 4; ++j) { mr[j] = 0.f; lr[j] = 0.f; }
#pragma unroll
    for (int n = 0; n < 4; ++n)
#pragma unroll
        for (int e = 0; e < 4; ++e) oacc[n][e] = 0.f;

    const int srow = tid >> 3, schk = tid & 7;
    const int sdst0 = srow * 64 + ((schk ^ (srow & 7)) << 3);
    const int sdst1 = (srow + 32) * 64 + ((schk ^ (srow & 7)) << 3);

    #define IN_BAND(kt_) ({ int _a = (kt_) - (q0 + 63); int _b = q0 - ((kt_) + 63); \
                            int _d = _a > 0 ? _a : (_b > 0 ? _b : 0); _d <= 160; })

    bool diagCur = IN_BAND(0);
    half8 rk0 = *(const half8*)(k  + (size_t)(srow) * DM + hoff + schk * 8);
    half8 rk1 = *(const half8*)(k  + (size_t)(srow + 32) * DM + hoff + schk * 8);
    half8 rm0 = *(const half8*)(mixedT + (size_t)(hoff + srow) * SEQ + schk * 8);
    half8 rm1 = *(const half8*)(mixedT + (size_t)(hoff + srow + 32) * SEQ + schk * 8);
    half8 re0, re1;
    if (diagCur) {
        re0 = *(const half8*)(ek + (size_t)(srow) * DM + hoff + schk * 8);
        re1 = *(const half8*)(ek + (size_t)(srow + 32) * DM + hoff + schk * 8);
    }

    for (int kt = 0; kt < SEQ; kt += 64) {
        __syncthreads();
        *(half8*)&Kt[sdst0] = rk0; *(half8*)&Kt[sdst1] = rk1;
        *(half8*)&Mt[sdst0] = rm0; *(half8*)&Mt[sdst1] = rm1;
        if (diagCur) { *(half8*)&Et[sdst0] = re0; *(half8*)&Et[sdst1] = re1; }
        __syncthreads();
        const bool diagNext = (kt + 64 < SEQ) && IN_BAND(kt + 64);
        if (kt + 64 < SEQ) {
            const int nt = kt + 64;
            rk0 = *(const half8*)(k  + (size_t)(nt + srow) * DM + hoff + schk * 8);
            rk1 = *(const half8*)(k  + (size_t)(nt + srow + 32) * DM + hoff + schk * 8);
            rm0 = *(const half8*)(mixedT + (size_t)(hoff + srow) * SEQ + nt + schk * 8);
            rm1 = *(const half8*)(mixedT + (size_t)(hoff + srow + 32) * SEQ + nt + schk * 8);
            if (diagNext) {
                re0 = *(const half8*)(ek + (size_t)(nt + srow) * DM + hoff + schk * 8);
                re1 = *(const half8*)(ek + (size_t)(nt + srow + 32) * DM + hoff + schk * 8);
            }
        }

        // ---- QK^T (always) and EQ*EK^T (band tiles only)
        f32x4 sa[4], se[4];
#pragma unroll
        for (int n = 0; n < 4; ++n)
#pragma unroll
            for (int e = 0; e < 4; ++e) { sa[n][e] = 0.f; se[n][e] = 0.f; }
#pragma unroll
        for (int kk = 0; kk < 2; ++kk)
#pragma unroll
            for (int nf = 0; nf < 4; ++nf) {
                const int rrow = lo + 16 * nf;
                const int coff = rrow * 64 + (((hi + 4 * kk) ^ (rrow & 7)) << 3);
                half8 kb = *(const half8*)&Kt[coff];
                sa[nf] = __builtin_amdgcn_mfma_f32_16x16x32_f16(qa[kk], kb, sa[nf], 0, 0, 0);
            }
        if (diagCur) {
#pragma unroll
            for (int kk = 0; kk < 2; ++kk)
#pragma unroll
                for (int nf = 0; nf < 4; ++nf) {
                    const int rrow = lo + 16 * nf;
                    const int coff = rrow * 64 + (((hi + 4 * kk) ^ (rrow & 7)) << 3);
                    half8 eb = *(const half8*)&Et[coff];
                    se[nf] = __builtin_amdgcn_mfma_f32_16x16x32_f16(ea[kk], eb, se[nf], 0, 0, 0);
                }
        }

        // ---- logits + defer-max check
        float lg[4][4];
        bool exc = false;
        const int qrow = q0 + wv * 16 + hi * 4;
        if (diagCur) {
#pragma unroll
            for (int nf = 0; nf < 4; ++nf) {
                const int key = kt + nf * 16 + lo;
#pragma unroll
                for (int j = 0; j < 4; ++j) {
                    int dd = qrow + j - key; dd = dd < 0 ? -dd : dd;
                    const float dec = exp2f(-0.14426950408889634f * (float)dd);
                    const float v = 0.125f * sa[nf][j] + 0.0625f * se[nf][j] * dec;
                    lg[nf][j] = v;
                    exc |= (v > mr[j] + 8.f);
                }
            }
        } else {
#pragma unroll
            for (int nf = 0; nf < 4; ++nf)
#pragma unroll
                for (int j = 0; j < 4; ++j) {
                    const float v = 0.125f * sa[nf][j];
                    lg[nf][j] = v;
                    exc |= (v > mr[j] + 8.f);
                }
        }
        if (__any((int)exc)) {                       // rare rescale path
#pragma unroll
            for (int j = 0; j < 4; ++j) {
                float tm = fmaxf(fmaxf(lg[0][j], lg[1][j]), fmaxf(lg[2][j], lg[3][j]));
#pragma unroll
                for (int off = 8; off >= 1; off >>= 1) tm = fmaxf(tm, __shfl_xor(tm, off));
                const float mnew = fmaxf(mr[j], tm);
                const float corr = __expf(mr[j] - mnew);
                lr[j] *= corr; mr[j] = mnew;
#pragma unroll
                for (int nfd = 0; nfd < 4; ++nfd) oacc[nfd][j] *= corr;
            }
        }
        // ---- P = exp(lg - m), lane-local l accumulation, P -> LDS (f16)
        _Float16* Pw = Pt[wv];
#pragma unroll
        for (int nf = 0; nf < 4; ++nf) {
            half4v pv;
#pragma unroll
            for (int j = 0; j < 4; ++j) {
                const float p = __expf(lg[nf][j] - mr[j]);
                lr[j] += p;
                pv[j] = (_Float16)p;
            }
            *(half4v*)&Pw[(lo + 16 * nf) * 18 + hi * 4] = pv;
        }
        __asm__ volatile("s_waitcnt lgkmcnt(0)" ::: "memory");

        // ---- PV: oacc += P * mixed
#pragma unroll
        for (int kk = 0; kk < 2; ++kk) {
            half8 mb[4];
#pragma unroll
            for (int nfd = 0; nfd < 4; ++nfd) {
                const int rrow = lo + 16 * nfd;
                mb[nfd] = *(const half8*)&Mt[rrow * 64 + (((hi + 4 * kk) ^ (rrow & 7)) << 3)];
            }
            half8 pa;
#pragma unroll
            for (int e = 0; e < 8; ++e)
                pa[e] = Pw[(kk * 32 + hi * 8 + e) * 18 + lo];
#pragma unroll
            for (int nfd = 0; nfd < 4; ++nfd)
                oacc[nfd] = __builtin_amdgcn_mfma_f32_16x16x32_f16(pa, mb[nfd], oacc[nfd], 0, 0, 0);
        }
        diagCur = diagNext;
    }
    #undef IN_BAND

    // ---- epilogue: reduce l over the 16-lane row group, normalize, store
#pragma unroll
    for (int j = 0; j < 4; ++j) {
#pragma unroll
        for (int off = 8; off >= 1; off >>= 1) lr[j] += __shfl_xor(lr[j], off);
    }
    const int qrow = q0 + wv * 16 + hi * 4;
#pragma unroll
    for (int nfd = 0; nfd < 4; ++nfd) {
        const int d = hoff + lo + 16 * nfd;
#pragma unroll
        for (int j = 0; j < 4; ++j)
            ctx[(size_t)(qrow + j) * DM + d] = (__bf16)(oacc[nfd][j] / lr[j]);
    }
}

// --------------------------------------------- layer norm, FP32 OUTPUT
__global__ __launch_bounds__(256) void lnorm_f32(
    const float* __restrict__ res, const float* __restrict__ g,
    const float* __restrict__ b, float* __restrict__ out)
{
    const int row = blockIdx.x, tid = threadIdx.x;
    const int wave = tid >> 6, lane = tid & 63;
    __shared__ float red[8];
    const float4 x = reinterpret_cast<const float4*>(res + (size_t)row * DM)[tid];
    float s  = x.x + x.y + x.z + x.w;
    float s2 = x.x * x.x + x.y * x.y + x.z * x.z + x.w * x.w;
#pragma unroll
    for (int off = 32; off >= 1; off >>= 1) {
        s  += __shfl_xor(s, off);
        s2 += __shfl_xor(s2, off);
    }
    if (lane == 0) { red[wave] = s; red[4 + wave] = s2; }
    __syncthreads();
    s  = red[0] + red[1] + red[2] + red[3];
    s2 = red[4] + red[5] + red[6] + red[7];
    const float mu  = s * (1.f / DM);
    const float var = s2 * (1.f / DM) - mu * mu;
    const float inv = rsqrtf(var + 1e-5f);
    const int col = tid * 4;
    float4 o;
    o.x = (x.x - mu) * inv * g[col + 0] + b[col + 0];
    o.y = (x.y - mu) * inv * g[col + 1] + b[col + 1];
    o.z = (x.z - mu) * inv * g[col + 2] + b[col + 2];
    o.w = (x.w - mu) * inv * g[col + 3] + b[col + 3];
    reinterpret_cast<float4*>(out + (size_t)row * DM)[tid] = o;
}

// ---------------------------------------------------------------- launch
// OUTPUT IS FP32. r10 configuration — session best (291.5 us measured).
// ws layout (~34.3 MB):
//   [0,4M)    hsb bf16        -> overlaid by mixedT f16 (hsb dead after g1)
//   [4,16M)   w0..w5 bf16 (Wq,Wk,Wv,Weq,Wek,Wo), 2MB each
//   [16,18M)  w6 = Wsup bf16
//   [18,22M)  qf f16   [22,26M) kf f16   } res f32 overlays [18,26M) post-attn
//   [26,30M)  eqf f16  [30,34M) ekf f16
//   [34M..)   cAT (128K), sAT (128K), bsup (4K)   ([h][s] layout)
// d_out staging: vT f16 [0,4M), supT f16 [4,8M) (TRANSPOSED [col][s]);
// dead after mixT2; ctx bf16 occupies [0,4M); lnorm rewrites full 8MB fp32.
extern "C" void kernel_launch(void* const* d_in, const int* in_sizes, int n_in,
                              void* d_out, int out_size, void* d_ws, size_t ws_size,
                              hipStream_t stream) {
    const float* hs   = (const float*)d_in[0];
    const float* Wq   = (const float*)d_in[1];
    const float* bq   = (const float*)d_in[2];
    const float* Wk   = (const float*)d_in[3];
    const float* bk   = (const float*)d_in[4];
    const float* Wv   = (const float*)d_in[5];
    const float* bv   = (const float*)d_in[6];
    const float* Wo   = (const float*)d_in[7];
    const float* bo   = (const float*)d_in[8];
    const float* Weq  = (const float*)d_in[9];
    const float* beq  = (const float*)d_in[10];
    const float* Wek  = (const float*)d_in[11];
    const float* bek  = (const float*)d_in[12];
    const float* ampw = (const float*)d_in[13];
    const float* ampb = (const float*)d_in[14];
    const float* phw  = (const float*)d_in[15];
    const float* phb  = (const float*)d_in[16];
    const float* mixw = (const float*)d_in[17];
    const float* mixb = (const float*)d_in[18];
    const float* lng  = (const float*)d_in[19];
    const float* lnb  = (const float*)d_in[20];
    float* out = (float*)d_out;

    static const int expect[21] = {
        2097152, 1048576, 1024, 1048576, 1024, 1048576, 1024, 1048576, 1024,
        1048576, 1024, 1048576, 1024, 16384, 16, 16384, 16, 65536, 1024,
        1024, 1024};
    bool ok = (n_in == 21) && (out_size == 2097152);
    if (ok) for (int i = 0; i < 21; ++i) ok = ok && (in_sizes[i] == expect[i]);
    if (!ok) {
        zero_out<<<(out_size + 255) / 256, 256, 0, stream>>>(out, out_size);
        return;
    }

    char* ws = (char*)d_ws;
    __bf16*   hsb = (__bf16*)ws;
    __bf16*   w0  = (__bf16*)(ws + (4  << 20));
    __bf16*   w1  = (__bf16*)(ws + (6  << 20));
    __bf16*   w2  = (__bf16*)(ws + (8  << 20));
    __bf16*   w3  = (__bf16*)(ws + (10 << 20));
    __bf16*   w4  = (__bf16*)(ws + (12 << 20));
    __bf16*   w5  = (__bf16*)(ws + (14 << 20));
    __bf16*   w6  = (__bf16*)(ws + (16 << 20));
    _Float16* qf  = (_Float16*)(ws + (18 << 20));
    _Float16* kf  = (_Float16*)(ws + (22 << 20));
    _Float16* eqf = (_Float16*)(ws + (26 << 20));
    _Float16* ekf = (_Float16*)(ws + (30 << 20));
    float*    cAT = (float*)(ws + (34 << 20));
    float*    sAT = cAT + SEQ * NH;
    float*    bsup = sAT + SEQ * NH;
    _Float16* mxT = (_Float16*)hsb;            // overlay: hsb dead after g1
    float*    res = (float*)(ws + (18 << 20)); // overlay: q/k dead after attn
    _Float16* vT   = (_Float16*)d_out;
    _Float16* supT = (_Float16*)((char*)d_out + (4 << 20));
    __bf16*   ctx  = (__bf16*)d_out;

    PrepArgs p;
    p.csrc[0] = Wq;  p.cdst[0] = w0;
    p.csrc[1] = Wk;  p.cdst[1] = w1;
    p.csrc[2] = Wv;  p.cdst[2] = w2;
    p.csrc[3] = Weq; p.cdst[3] = w3;
    p.csrc[4] = Wek; p.cdst[4] = w4;
    p.csrc[5] = Wo;  p.cdst[5] = w5;
    p.csrc[6] = hs;                p.cdst[6] = hsb;
    p.csrc[7] = hs + SEQ * DM / 2; p.cdst[7] = hsb + SEQ * DM / 2;
    p.mixw = mixw; p.Wv = Wv; p.bv = bv; p.mixb = mixb;
    p.w6 = w6; p.bsup = bsup;
    p.hs = hs;
    p.amp_w = ampw; p.amp_b = ampb; p.ph_w = phw; p.ph_b = phb;
    p.cAT = cAT; p.sAT = sAT;
    prep_all<<<7168, 256, 0, stream>>>(p);

    GemmBatch g1 = {};
    g1.A = hsb;
    g1.W[0] = w0; g1.bias[0] = bq;   g1.out[0] = qf;   g1.mode[0] = 3;
    g1.W[1] = w1; g1.bias[1] = bk;   g1.out[1] = kf;   g1.mode[1] = 3;
    g1.W[2] = w2; g1.bias[2] = bv;   g1.out[2] = vT;   g1.mode[2] = 4;
    g1.W[3] = w3; g1.bias[3] = beq;  g1.out[3] = eqf;  g1.mode[3] = 3;
    g1.W[4] = w4; g1.bias[4] = bek;  g1.out[4] = ekf;  g1.mode[4] = 3;
    g1.W[5] = w6; g1.bias[5] = bsup; g1.out[5] = supT; g1.mode[5] = 4;
    g1.resid = nullptr;
    gemm_bt<<<dim3(DM / 128, SEQ / 128, 6), 256, 0, stream>>>(g1);

    mixT2<<<1024, 256, 0, stream>>>(vT, supT, cAT, sAT, mxT);

    attn_mfma<<<512, 256, 0, stream>>>(qf, kf, eqf, ekf, mxT, ctx);

    GemmBatch g3 = {};
    g3.A = ctx;
    g3.W[0] = w5; g3.bias[0] = bo; g3.out[0] = res; g3.mode[0] = 2;
    g3.resid = hs;
    gemm_bt<<<dim3(DM / 128, SEQ / 128, 1), 256, 0, stream>>>(g3);

    lnorm_f32<<<SEQ, 256, 0, stream>>>(res, lng, lnb, out);
}